// Round 2
// baseline (2172.878 us; speedup 1.0000x reference)
//
#include <hip/hip_runtime.h>
#include <hip/hip_bf16.h>

// SIRLayer inference, MI355X. All float tensors are fp32 (per reference),
// coors int32. Two-pass: K1 (gate + vfe0 + scatter-max), K2 (vfe1 + shortcut).
// d_out [N,64] fp32 doubles as p0 scratch between K1 and K2 (in-place update).
// d_ws holds the voxel max buffer [V,64] fp32-as-uint, zeroed each call.

#define VVOX 65536

// ---------------------------------------------------------------------------
// K1: per point -> rel MLP gate -> gated feats -> vfe0 -> p0 (store to out)
//     + atomicMax (uint bits of non-negative fp32) into voxel buffer.
// ---------------------------------------------------------------------------
__global__ void __launch_bounds__(256)
sir_k1(const float* __restrict__ xyz,
       const float* __restrict__ pfeat,
       const float* __restrict__ fclu,
       const int* __restrict__ coors,
       const float* __restrict__ rw0,
       const float* __restrict__ rg0,
       const float* __restrict__ rb0,
       const float* __restrict__ rw1,
       const float* __restrict__ rg1,
       const float* __restrict__ rb1,
       const float* __restrict__ vw0,
       const float* __restrict__ vg0,
       const float* __restrict__ vb0,
       unsigned int* __restrict__ vmax,   // [V*64] fp32 bits, pre-zeroed
       float* __restrict__ p0out,         // = d_out, [N*64] fp32
       int npts)
{
    __shared__ float s_w0[48];    // rel_w0 [i*16+j], prescaled by g0[j]
    __shared__ float s_b0[16];
    __shared__ float s_w1t[1024]; // rel_w1 transposed: [k*16+j] = w1[j][k]*g1[k]
    __shared__ float s_b1[64];
    __shared__ float s_vw0[4096]; // vfe_w0 [k*64+c], prescaled by vg0[c]
    __shared__ float s_vb0[64];

    const int t = threadIdx.x;
    for (int i = t; i < 48; i += 256) s_w0[i] = rw0[i] * rg0[i & 15];
    if (t < 16) s_b0[t] = rb0[t];
    for (int i = t; i < 1024; i += 256) {
        int k = i >> 4, j = i & 15;
        s_w1t[i] = rw1[j * 64 + k] * rg1[k];
    }
    if (t < 64) s_b1[t] = rb1[t];
    for (int i = t; i < 4096; i += 256) s_vw0[i] = vw0[i] * vg0[i & 63];
    if (t < 64) s_vb0[t] = vb0[t];
    __syncthreads();

    const int pt = blockIdx.x * 256 + t;
    if (pt >= npts) return;

    // feats = concat(xyz, pfeat)   (XYZ_NORM == 1)
    float f[64];
    {
        const float* xr = xyz + (size_t)pt * 3;
        f[0] = xr[0]; f[1] = xr[1]; f[2] = xr[2];
        const float* fr = pfeat + (size_t)pt * 61;
        #pragma unroll
        for (int k = 0; k < 61; ++k) f[3 + k] = fr[k];
    }

    // rel MLP layer 0: h = relu(fc @ w0 * g0 + b0), 16 wide
    const float* cr = fclu + (size_t)pt * 3;
    const float c0 = cr[0], c1 = cr[1], c2 = cr[2];
    float h[16];
    #pragma unroll
    for (int j = 0; j < 16; ++j) {
        float v = s_b0[j];
        v = fmaf(c0, s_w0[j], v);
        v = fmaf(c1, s_w0[16 + j], v);
        v = fmaf(c2, s_w0[32 + j], v);
        h[j] = fmaxf(v, 0.f);
    }

    // main loop: gate_k = relu(h . w1[:,k] + b1_k), gated_k = f_k * gate_k,
    //            acc[c] += gated_k * vfe_w0[k][c]
    float acc[64];
    #pragma unroll
    for (int c = 0; c < 64; ++c) acc[c] = s_vb0[c];

    for (int k = 0; k < 64; ++k) {
        float g = s_b1[k];
        const float* w1k = s_w1t + k * 16;
        #pragma unroll
        for (int j = 0; j < 16; ++j) g = fmaf(h[j], w1k[j], g);
        g = fmaxf(g, 0.f);
        const float gk = f[k] * g;
        const float* wk = s_vw0 + k * 64;
        #pragma unroll
        for (int c = 0; c < 64; ++c) acc[c] = fmaf(gk, wk[c], acc[c]);
    }

    // relu -> p0; store row; scatter-max (skip zeros; buffer pre-zeroed)
    const int vox = coors[pt];
    unsigned int* vrow = vmax + (size_t)vox * 64;
    float4* orow = reinterpret_cast<float4*>(p0out + (size_t)pt * 64);
    #pragma unroll
    for (int q = 0; q < 16; ++q) {
        float4 u;
        u.x = fmaxf(acc[q * 4 + 0], 0.f);
        u.y = fmaxf(acc[q * 4 + 1], 0.f);
        u.z = fmaxf(acc[q * 4 + 2], 0.f);
        u.w = fmaxf(acc[q * 4 + 3], 0.f);
        if (u.x > 0.f) atomicMax(vrow + q * 4 + 0, __float_as_uint(u.x));
        if (u.y > 0.f) atomicMax(vrow + q * 4 + 1, __float_as_uint(u.y));
        if (u.z > 0.f) atomicMax(vrow + q * 4 + 2, __float_as_uint(u.z));
        if (u.w > 0.f) atomicMax(vrow + q * 4 + 3, __float_as_uint(u.w));
        orow[q] = u;
    }
}

// ---------------------------------------------------------------------------
// K2: p1 = relu(concat(p0, v0[coor]) @ vfe_w1 * g1 + b1) + concat(xyz, pfeat)
//     reads p0 from d_out, overwrites d_out in place (own row only).
// ---------------------------------------------------------------------------
__global__ void __launch_bounds__(256)
sir_k2(const float* __restrict__ xyz,
       const float* __restrict__ pfeat,
       const int* __restrict__ coors,
       const float* __restrict__ vw1,
       const float* __restrict__ vg1,
       const float* __restrict__ vb1,
       const float* __restrict__ vmaxf,   // [V*64] fp32 (bits written by K1)
       float* __restrict__ io,            // d_out: in p0, out result
       int npts)
{
    __shared__ float s_w[8192];  // vfe_w1 [k*64+c], k<128, prescaled vg1[c]
    __shared__ float s_b[64];
    const int t = threadIdx.x;
    for (int i = t; i < 8192; i += 256) s_w[i] = vw1[i] * vg1[i & 63];
    if (t < 64) s_b[t] = vb1[t];
    __syncthreads();

    const int pt = blockIdx.x * 256 + t;
    if (pt >= npts) return;

    float acc[64];
    #pragma unroll
    for (int c = 0; c < 64; ++c) acc[c] = s_b[c];

    // first 64 K: p0 row (fp32 from d_out)
    const float4* prow = reinterpret_cast<const float4*>(io + (size_t)pt * 64);
    for (int q = 0; q < 16; ++q) {
        const float4 u = prow[q];
        const float pv[4] = { u.x, u.y, u.z, u.w };
        const float* wk = s_w + q * 4 * 64;
        #pragma unroll
        for (int i = 0; i < 4; ++i) {
            const float pk = pv[i];
            #pragma unroll
            for (int c = 0; c < 64; ++c) acc[c] = fmaf(pk, wk[i * 64 + c], acc[c]);
        }
    }

    // second 64 K: gathered voxel row (fp32)
    const int vox = coors[pt];
    const float4* vrow = reinterpret_cast<const float4*>(vmaxf + (size_t)vox * 64);
    for (int q = 0; q < 16; ++q) {
        const float4 u = vrow[q];
        const float vv[4] = { u.x, u.y, u.z, u.w };
        const float* wk = s_w + (64 + q * 4) * 64;
        #pragma unroll
        for (int i = 0; i < 4; ++i) {
            const float vk = vv[i];
            #pragma unroll
            for (int c = 0; c < 64; ++c) acc[c] = fmaf(vk, wk[i * 64 + c], acc[c]);
        }
    }

    // relu + shortcut (original concat(xyz, pfeat)) + store
    const float* xr = xyz + (size_t)pt * 3;
    const float* fr = pfeat + (size_t)pt * 61;
    float4* orow = reinterpret_cast<float4*>(io + (size_t)pt * 64);
    #pragma unroll
    for (int q = 0; q < 16; ++q) {
        float4 u;
        const int c = q * 4;
        const float s0 = (c + 0 < 3) ? xr[c + 0] : fr[c - 3];
        const float s1 = (c + 1 < 3) ? xr[c + 1] : fr[c - 2];
        const float s2 = (c + 2 < 3) ? xr[c + 2] : fr[c - 1];
        const float s3 = (c + 3 < 3) ? xr[c + 3] : fr[c + 0];
        u.x = fmaxf(acc[c + 0], 0.f) + s0;
        u.y = fmaxf(acc[c + 1], 0.f) + s1;
        u.z = fmaxf(acc[c + 2], 0.f) + s2;
        u.w = fmaxf(acc[c + 3], 0.f) + s3;
        orow[q] = u;
    }
}

extern "C" void kernel_launch(void* const* d_in, const int* in_sizes, int n_in,
                              void* d_out, int out_size, void* d_ws, size_t ws_size,
                              hipStream_t stream) {
    const float* xyz   = (const float*)d_in[0];
    const float* pfeat = (const float*)d_in[1];
    const float* fclu  = (const float*)d_in[2];
    const int*   coors = (const int*)d_in[3];
    const float* rw0 = (const float*)d_in[4];
    const float* rg0 = (const float*)d_in[5];
    const float* rb0 = (const float*)d_in[6];
    const float* rw1 = (const float*)d_in[7];
    const float* rg1 = (const float*)d_in[8];
    const float* rb1 = (const float*)d_in[9];
    const float* vw0 = (const float*)d_in[10];
    const float* vg0 = (const float*)d_in[11];
    const float* vb0 = (const float*)d_in[12];
    const float* vw1 = (const float*)d_in[13];
    const float* vg1 = (const float*)d_in[14];
    const float* vb1 = (const float*)d_in[15];

    float*        out  = (float*)d_out;
    unsigned int* vmax = (unsigned int*)d_ws;
    const int npts = in_sizes[3];
    const int blocks = (npts + 255) / 256;

    // zero voxel-max buffer (identity for max over relu outputs; empty -> 0)
    hipMemsetAsync(d_ws, 0, (size_t)VVOX * 64 * sizeof(float), stream);

    hipLaunchKernelGGL(sir_k1, dim3(blocks), dim3(256), 0, stream,
                       xyz, pfeat, fclu, coors,
                       rw0, rg0, rb0, rw1, rg1, rb1,
                       vw0, vg0, vb0, vmax, out, npts);

    hipLaunchKernelGGL(sir_k2, dim3(blocks), dim3(256), 0, stream,
                       xyz, pfeat, coors,
                       vw1, vg1, vb1, (const float*)d_ws, out, npts);
}

// Round 3
// 1667.963 us; speedup vs baseline: 1.3027x; 1.3027x over previous
//
#include <hip/hip_runtime.h>
#include <hip/hip_bf16.h>

// SIRLayer inference, MI355X. All float tensors fp32, coors int32.
// K1: gate + vfe0 + filtered scatter-max (read-before-atomic; safe because
//     voxel max is monotone non-decreasing and any stale read <= current).
// K2: vfe1 + shortcut, in-place on d_out.
// d_out [N,64] fp32 doubles as p0 scratch between K1 and K2.
// d_ws holds the voxel max buffer [V,64] fp32-as-uint, zeroed each call.

#define VVOX 65536

// ---------------------------------------------------------------------------
// K1: per point -> rel MLP gate -> gated feats -> vfe0 -> p0 (store to out)
//     + filtered atomicMax (uint bits of non-negative fp32) into voxel buffer.
// ---------------------------------------------------------------------------
__global__ void __launch_bounds__(256)
sir_k1(const float* __restrict__ xyz,
       const float* __restrict__ pfeat,
       const float* __restrict__ fclu,
       const int* __restrict__ coors,
       const float* __restrict__ rw0,
       const float* __restrict__ rg0,
       const float* __restrict__ rb0,
       const float* __restrict__ rw1,
       const float* __restrict__ rg1,
       const float* __restrict__ rb1,
       const float* __restrict__ vw0,
       const float* __restrict__ vg0,
       const float* __restrict__ vb0,
       unsigned int* __restrict__ vmax,   // [V*64] fp32 bits, pre-zeroed
       float* __restrict__ p0out,         // = d_out, [N*64] fp32
       int npts)
{
    __shared__ float s_w0[48];    // rel_w0 [i*16+j], prescaled by g0[j]
    __shared__ float s_b0[16];
    __shared__ float s_w1t[1024]; // rel_w1 transposed: [k*16+j] = w1[j][k]*g1[k]
    __shared__ float s_b1[64];
    __shared__ float s_vw0[4096]; // vfe_w0 [k*64+c], prescaled by vg0[c]
    __shared__ float s_vb0[64];

    const int t = threadIdx.x;
    for (int i = t; i < 48; i += 256) s_w0[i] = rw0[i] * rg0[i & 15];
    if (t < 16) s_b0[t] = rb0[t];
    for (int i = t; i < 1024; i += 256) {
        int k = i >> 4, j = i & 15;
        s_w1t[i] = rw1[j * 64 + k] * rg1[k];
    }
    if (t < 64) s_b1[t] = rb1[t];
    for (int i = t; i < 4096; i += 256) s_vw0[i] = vw0[i] * vg0[i & 63];
    if (t < 64) s_vb0[t] = vb0[t];
    __syncthreads();

    const int pt = blockIdx.x * 256 + t;
    if (pt >= npts) return;

    // feats = concat(xyz, pfeat)   (XYZ_NORM == 1)
    float f[64];
    {
        const float* xr = xyz + (size_t)pt * 3;
        f[0] = xr[0]; f[1] = xr[1]; f[2] = xr[2];
        const float* fr = pfeat + (size_t)pt * 61;
        #pragma unroll
        for (int k = 0; k < 61; ++k) f[3 + k] = fr[k];
    }

    // rel MLP layer 0: h = relu(fc @ w0 * g0 + b0), 16 wide
    const float* cr = fclu + (size_t)pt * 3;
    const float c0 = cr[0], c1 = cr[1], c2 = cr[2];
    float h[16];
    #pragma unroll
    for (int j = 0; j < 16; ++j) {
        float v = s_b0[j];
        v = fmaf(c0, s_w0[j], v);
        v = fmaf(c1, s_w0[16 + j], v);
        v = fmaf(c2, s_w0[32 + j], v);
        h[j] = fmaxf(v, 0.f);
    }

    // main loop: gate_k = relu(h . w1[:,k] + b1_k), gated_k = f_k * gate_k,
    //            acc[c] += gated_k * vfe_w0[k][c]
    float acc[64];
    #pragma unroll
    for (int c = 0; c < 64; ++c) acc[c] = s_vb0[c];

    for (int k = 0; k < 64; ++k) {
        float g = s_b1[k];
        const float* w1k = s_w1t + k * 16;
        #pragma unroll
        for (int j = 0; j < 16; ++j) g = fmaf(h[j], w1k[j], g);
        g = fmaxf(g, 0.f);
        const float gk = f[k] * g;
        const float* wk = s_vw0 + k * 64;
        #pragma unroll
        for (int c = 0; c < 64; ++c) acc[c] = fmaf(gk, wk[c], acc[c]);
    }

    // relu -> p0; store row; FILTERED scatter-max.
    // Safe: vmax cells are monotone non-decreasing and >= 0; a plain load
    // returns some past value stale <= current. If p <= stale, then the
    // final value >= p already -> skip atomic. Non-negative fp32 compare
    // == uint compare on the bit patterns.
    const int vox = coors[pt];
    unsigned int* vrow = vmax + (size_t)vox * 64;
    const uint4* vrow4 = reinterpret_cast<const uint4*>(vrow);
    float4* orow = reinterpret_cast<float4*>(p0out + (size_t)pt * 64);
    #pragma unroll
    for (int q = 0; q < 16; ++q) {
        const uint4 cur = vrow4[q];
        float4 u;
        u.x = fmaxf(acc[q * 4 + 0], 0.f);
        u.y = fmaxf(acc[q * 4 + 1], 0.f);
        u.z = fmaxf(acc[q * 4 + 2], 0.f);
        u.w = fmaxf(acc[q * 4 + 3], 0.f);
        orow[q] = u;
        if (__float_as_uint(u.x) > cur.x) atomicMax(vrow + q * 4 + 0, __float_as_uint(u.x));
        if (__float_as_uint(u.y) > cur.y) atomicMax(vrow + q * 4 + 1, __float_as_uint(u.y));
        if (__float_as_uint(u.z) > cur.z) atomicMax(vrow + q * 4 + 2, __float_as_uint(u.z));
        if (__float_as_uint(u.w) > cur.w) atomicMax(vrow + q * 4 + 3, __float_as_uint(u.w));
    }
}

// ---------------------------------------------------------------------------
// K2: p1 = relu(concat(p0, v0[coor]) @ vfe_w1 * g1 + b1) + concat(xyz, pfeat)
//     reads p0 from d_out, overwrites d_out in place (own row only).
// ---------------------------------------------------------------------------
__global__ void __launch_bounds__(256)
sir_k2(const float* __restrict__ xyz,
       const float* __restrict__ pfeat,
       const int* __restrict__ coors,
       const float* __restrict__ vw1,
       const float* __restrict__ vg1,
       const float* __restrict__ vb1,
       const float* __restrict__ vmaxf,   // [V*64] fp32 (bits written by K1)
       float* __restrict__ io,            // d_out: in p0, out result
       int npts)
{
    __shared__ float s_w[8192];  // vfe_w1 [k*64+c], k<128, prescaled vg1[c]
    __shared__ float s_b[64];
    const int t = threadIdx.x;
    for (int i = t; i < 8192; i += 256) s_w[i] = vw1[i] * vg1[i & 63];
    if (t < 64) s_b[t] = vb1[t];
    __syncthreads();

    const int pt = blockIdx.x * 256 + t;
    if (pt >= npts) return;

    float acc[64];
    #pragma unroll
    for (int c = 0; c < 64; ++c) acc[c] = s_b[c];

    // first 64 K: p0 row (fp32 from d_out)
    const float4* prow = reinterpret_cast<const float4*>(io + (size_t)pt * 64);
    for (int q = 0; q < 16; ++q) {
        const float4 u = prow[q];
        const float pv[4] = { u.x, u.y, u.z, u.w };
        const float* wk = s_w + q * 4 * 64;
        #pragma unroll
        for (int i = 0; i < 4; ++i) {
            const float pk = pv[i];
            #pragma unroll
            for (int c = 0; c < 64; ++c) acc[c] = fmaf(pk, wk[i * 64 + c], acc[c]);
        }
    }

    // second 64 K: gathered voxel row (fp32)
    const int vox = coors[pt];
    const float4* vrow = reinterpret_cast<const float4*>(vmaxf + (size_t)vox * 64);
    for (int q = 0; q < 16; ++q) {
        const float4 u = vrow[q];
        const float vv[4] = { u.x, u.y, u.z, u.w };
        const float* wk = s_w + (64 + q * 4) * 64;
        #pragma unroll
        for (int i = 0; i < 4; ++i) {
            const float vk = vv[i];
            #pragma unroll
            for (int c = 0; c < 64; ++c) acc[c] = fmaf(vk, wk[i * 64 + c], acc[c]);
        }
    }

    // relu + shortcut (original concat(xyz, pfeat)) + store
    const float* xr = xyz + (size_t)pt * 3;
    const float* fr = pfeat + (size_t)pt * 61;
    float4* orow = reinterpret_cast<float4*>(io + (size_t)pt * 64);
    #pragma unroll
    for (int q = 0; q < 16; ++q) {
        float4 u;
        const int c = q * 4;
        const float s0 = (c + 0 < 3) ? xr[c + 0] : fr[c - 3];
        const float s1 = (c + 1 < 3) ? xr[c + 1] : fr[c - 2];
        const float s2 = (c + 2 < 3) ? xr[c + 2] : fr[c - 1];
        const float s3 = (c + 3 < 3) ? xr[c + 3] : fr[c + 0];
        u.x = fmaxf(acc[c + 0], 0.f) + s0;
        u.y = fmaxf(acc[c + 1], 0.f) + s1;
        u.z = fmaxf(acc[c + 2], 0.f) + s2;
        u.w = fmaxf(acc[c + 3], 0.f) + s3;
        orow[q] = u;
    }
}

extern "C" void kernel_launch(void* const* d_in, const int* in_sizes, int n_in,
                              void* d_out, int out_size, void* d_ws, size_t ws_size,
                              hipStream_t stream) {
    const float* xyz   = (const float*)d_in[0];
    const float* pfeat = (const float*)d_in[1];
    const float* fclu  = (const float*)d_in[2];
    const int*   coors = (const int*)d_in[3];
    const float* rw0 = (const float*)d_in[4];
    const float* rg0 = (const float*)d_in[5];
    const float* rb0 = (const float*)d_in[6];
    const float* rw1 = (const float*)d_in[7];
    const float* rg1 = (const float*)d_in[8];
    const float* rb1 = (const float*)d_in[9];
    const float* vw0 = (const float*)d_in[10];
    const float* vg0 = (const float*)d_in[11];
    const float* vb0 = (const float*)d_in[12];
    const float* vw1 = (const float*)d_in[13];
    const float* vg1 = (const float*)d_in[14];
    const float* vb1 = (const float*)d_in[15];

    float*        out  = (float*)d_out;
    unsigned int* vmax = (unsigned int*)d_ws;
    const int npts = in_sizes[3];
    const int blocks = (npts + 255) / 256;

    // zero voxel-max buffer (identity for max over relu outputs; empty -> 0)
    hipMemsetAsync(d_ws, 0, (size_t)VVOX * 64 * sizeof(float), stream);

    hipLaunchKernelGGL(sir_k1, dim3(blocks), dim3(256), 0, stream,
                       xyz, pfeat, fclu, coors,
                       rw0, rg0, rb0, rw1, rg1, rb1,
                       vw0, vg0, vb0, vmax, out, npts);

    hipLaunchKernelGGL(sir_k2, dim3(blocks), dim3(256), 0, stream,
                       xyz, pfeat, coors,
                       vw1, vg1, vb1, (const float*)d_ws, out, npts);
}